// Round 17
// baseline (245.236 us; speedup 1.0000x reference)
//
#include <hip/hip_runtime.h>
#include <hip/hip_bf16.h>

#define BB 512
#define TT 300
#define IN_S 128
#define IN_D 64
#define HS 256
#define HD 128
#define CD 512  // 2*HD + HS

typedef __attribute__((ext_vector_type(8))) short bf16x8;
typedef __attribute__((ext_vector_type(4))) float f32x4;
typedef __attribute__((ext_vector_type(4))) unsigned uint4_t;
typedef unsigned short ushort_t;

static __device__ __forceinline__ ushort_t f2bf(float x) {
    unsigned u = __builtin_bit_cast(unsigned, x);
    unsigned r = (u + 0x7FFFu + ((u >> 16) & 1u)) >> 16;  // RNE
    return (ushort_t)r;
}
static __device__ __forceinline__ float bflo(unsigned u) {
    return __builtin_bit_cast(float, u << 16);
}
static __device__ __forceinline__ float bfhi(unsigned u) {
    return __builtin_bit_cast(float, u & 0xffff0000u);
}
static __device__ __forceinline__ unsigned cvt_pk(float lo, float hi) {
    unsigned r;
    asm("v_cvt_pk_bf16_f32 %0, %1, %2" : "=v"(r) : "v"(lo), "v"(hi));
    return r;
}

// ---------------------------------------------------------------------------
// prep: f32 weights -> bf16 workspace copies; fused RNN bias sums.
// ---------------------------------------------------------------------------
__global__ __launch_bounds__(256) void prep_kernel(
    const float* __restrict__ wd, const float* __restrict__ wihf, const float* __restrict__ wihb,
    const float* __restrict__ whhf, const float* __restrict__ whhb,
    const float* __restrict__ bif, const float* __restrict__ bhf,
    const float* __restrict__ bib, const float* __restrict__ bhb,
    ushort_t* __restrict__ wd_bf, ushort_t* __restrict__ wihf_bf, ushort_t* __restrict__ wihb_bf,
    ushort_t* __restrict__ whhf_bf, ushort_t* __restrict__ whhb_bf,
    float* __restrict__ bsf, float* __restrict__ bsb)
{
    const int i = blockIdx.x * 256 + threadIdx.x;  // < 16384
    if (i < HD * IN_D) wd_bf[i] = f2bf(wd[i]);
    wihf_bf[i] = f2bf(wihf[i]);
    wihb_bf[i] = f2bf(wihb[i]);
    whhf_bf[i] = f2bf(whhf[i]);
    whhb_bf[i] = f2bf(whhb[i]);
    if (i < HD) { bsf[i] = bif[i] + bhf[i]; bsb[i] = bib[i] + bhb[i]; }
}

// ---------------------------------------------------------------------------
// Kernel A (validated r0): static MLP + static head dot.
// ---------------------------------------------------------------------------
__global__ __launch_bounds__(256) void static_head_kernel(
    const float* __restrict__ xs, const int* __restrict__ norder,
    const float* __restrict__ w1, const float* __restrict__ b1,
    const float* __restrict__ w2, const float* __restrict__ b2,
    const float* __restrict__ fcw, const float* __restrict__ fcb,
    float* __restrict__ ds)
{
    __shared__ float xb[IN_S];
    __shared__ float s1[HS];
    __shared__ float red[4];
    const int b = blockIdx.x, tid = threadIdx.x;
    if (tid < IN_S) xb[tid] = xs[(size_t)b * IN_S + tid];
    __syncthreads();

    float a0 = 0.f, a1 = 0.f, a2 = 0.f, a3 = 0.f;
    {
        const float4* wsrc = (const float4*)(w1 + (size_t)tid * IN_S);
        const float4* x4 = (const float4*)xb;
#pragma unroll
        for (int i = 0; i < IN_S / 4; ++i) {
            float4 w = wsrc[i], x = x4[i];
            a0 = fmaf(w.x, x.x, a0); a1 = fmaf(w.y, x.y, a1);
            a2 = fmaf(w.z, x.z, a2); a3 = fmaf(w.w, x.w, a3);
        }
    }
    s1[tid] = fmaxf(b1[tid] + ((a0 + a1) + (a2 + a3)), 0.f);
    __syncthreads();

    a0 = a1 = a2 = a3 = 0.f;
    {
        const float4* wsrc = (const float4*)(w2 + (size_t)tid * HS);
        const float4* x4 = (const float4*)s1;
#pragma unroll
        for (int i = 0; i < HS / 4; ++i) {
            float4 w = wsrc[i], x = x4[i];
            a0 = fmaf(w.x, x.x, a0); a1 = fmaf(w.y, x.y, a1);
            a2 = fmaf(w.z, x.z, a2); a3 = fmaf(w.w, x.w, a3);
        }
    }
    float s2 = fmaxf(b2[tid] + ((a0 + a1) + (a2 + a3)), 0.f);

    const int n = norder[b];
    float p = s2 * fcw[(size_t)n * CD + tid];
#pragma unroll
    for (int o = 32; o >= 1; o >>= 1) p += __shfl_down(p, o);
    if ((tid & 63) == 0) red[tid >> 6] = p;
    __syncthreads();
    if (tid == 0) ds[b] = red[0] + red[1] + red[2] + red[3] + fcb[n];
}

// ---------------------------------------------------------------------------
// proj v16: v14's validated structure at HALF tile (64 rows) for 2x occupancy.
// LDS 24KB (d 16KB + x 8KB), 2400 blocks, __launch_bounds__(256,4).
// Every pattern (staging swizzle, scalar d-write, hoisted Bd, staging bounce,
// wide dwordx4 stores) is v14's code with the mt dimension removed.
// ---------------------------------------------------------------------------
__global__ __launch_bounds__(256, 4) void proj_kernel(
    const float* __restrict__ xd, const ushort_t* __restrict__ wd_bf,
    const float* __restrict__ bd,
    const ushort_t* __restrict__ wihf_bf, const ushort_t* __restrict__ wihb_bf,
    const float* __restrict__ bsf, const float* __restrict__ bsb,
    ushort_t* __restrict__ preF, ushort_t* __restrict__ preB)
{
    __shared__ char lds[24576];
    char* dbase = lds;            // [64][128] bf16 = 16KB, swizzled 256B rows
    char* xbase = lds + 16384;    // [64][64]  bf16 =  8KB, swizzled 128B rows
    const int tid = threadIdx.x;
    const int m0 = blockIdx.x * 64;

    {   // stage x -> bf16 LDS (16 f32/thread), logical byte L stored at L^swz
        const int row = tid >> 2, q = tid & 3;
        const int swz = (row & 7) << 4;
        const float4* src = (const float4*)(xd + (size_t)(m0 + row) * IN_D + q * 16);
        const float4 a = src[0], b = src[1], c = src[2], d = src[3];
        const uint4_t v0 = {cvt_pk(a.x, a.y), cvt_pk(a.z, a.w),
                            cvt_pk(b.x, b.y), cvt_pk(b.z, b.w)};
        const uint4_t v1 = {cvt_pk(c.x, c.y), cvt_pk(c.z, c.w),
                            cvt_pk(d.x, d.y), cvt_pk(d.z, d.w)};
        *(uint4_t*)(xbase + ((row * 128 + q * 32) ^ swz)) = v0;
        *(uint4_t*)(xbase + ((row * 128 + q * 32 + 16) ^ swz)) = v1;
    }
    __syncthreads();

    const int w = tid >> 6, l = tid & 63;
    const int lr = l & 15, lg = l >> 4;
    const int arow = w * 16 + lr;            // this wave's x/d row on lane lr
    const int aswz = (arow & 7) << 4;

    // ---- phase 1: d = relu(x @ wd^T + bd), wave w owns rows w*16..+15 ----
    {
        f32x4 acc1[8];
#pragma unroll
        for (int nt = 0; nt < 8; ++nt) acc1[nt] = (f32x4){0.f, 0.f, 0.f, 0.f};
#pragma unroll
        for (int kk = 0; kk < 2; ++kk) {
            const bf16x8 a1 = *(const bf16x8*)(xbase + ((arow * 128 + kk * 64 + lg * 16) ^ aswz));
            bf16x8 b[8];
#pragma unroll
            for (int nt = 0; nt < 8; ++nt)
                b[nt] = *(const bf16x8*)(wd_bf + (size_t)(nt * 16 + lr) * IN_D + kk * 32 + lg * 8);
#pragma unroll
            for (int nt = 0; nt < 8; ++nt)
                acc1[nt] = __builtin_amdgcn_mfma_f32_16x16x32_bf16(a1, b[nt], acc1[nt], 0, 0, 0);
        }
#pragma unroll
        for (int nt = 0; nt < 8; ++nt) {
            const float bj = bd[nt * 16 + lr];
            const int col2 = (nt * 16 + lr) * 2;
#pragma unroll
            for (int r = 0; r < 4; ++r) {
                const int row = w * 16 + lg * 4 + r;
                const float v = fmaxf(acc1[nt][r] + bj, 0.f);
                *(ushort_t*)(dbase + ((row * 256 + col2) ^ ((row & 7) << 4))) = (ushort_t)cvt_pk(v, v);
            }
        }
    }
    __syncthreads();

    // ---- phase 2: pre = d @ wih^T + bs (both mats), A = d rows (hoisted) ----
    bf16x8 Bd[4];
#pragma unroll
    for (int kk = 0; kk < 4; ++kk)
        Bd[kk] = *(const bf16x8*)(dbase + ((arow * 256 + kk * 64 + lg * 16) ^ aswz));
    __syncthreads();   // all waves hoisted -> dbase free for output staging

#pragma unroll
    for (int mat = 0; mat < 2; ++mat) {
        const ushort_t* wm = mat ? wihb_bf : wihf_bf;
        const float* bs = mat ? bsb : bsf;
        ushort_t* outp = mat ? preB : preF;

        f32x4 acc2[8];
#pragma unroll
        for (int nt = 0; nt < 8; ++nt) acc2[nt] = (f32x4){0.f, 0.f, 0.f, 0.f};
#pragma unroll
        for (int kk = 0; kk < 4; ++kk) {
            bf16x8 b[8];
#pragma unroll
            for (int nt = 0; nt < 8; ++nt)
                b[nt] = *(const bf16x8*)(wm + (size_t)(nt * 16 + lr) * HD + kk * 32 + lg * 8);
#pragma unroll
            for (int nt = 0; nt < 8; ++nt)
                acc2[nt] = __builtin_amdgcn_mfma_f32_16x16x32_bf16(Bd[kk], b[nt], acc2[nt], 0, 0, 0);
        }

        // stage 64x128 output tile into dbase, then store 1KB-wide per instr
#pragma unroll
        for (int nt = 0; nt < 8; ++nt) {
            const float bj = bs[nt * 16 + lr];
            const int col2 = (nt * 16 + lr) * 2;
#pragma unroll
            for (int r = 0; r < 4; ++r) {
                const int rr = w * 16 + lg * 4 + r;   // staging row = m-row in tile
                const float v = acc2[nt][r] + bj;
                *(ushort_t*)(dbase + ((rr * 256 + col2) ^ ((rr & 7) << 4))) = (ushort_t)cvt_pk(v, v);
            }
        }
        __syncthreads();
#pragma unroll
        for (int k = 0; k < 4; ++k) {
            const int seg = tid + k * 256;            // 0..1023
            const int rr = seg >> 4, sg = seg & 15;
            const uint4_t val = *(const uint4_t*)(dbase + ((rr * 256 + sg * 16) ^ ((rr & 7) << 4)));
            *(uint4_t*)(outp + (size_t)(m0 + rr) * HD + sg * 8) = val;
        }
        if (mat == 0) __syncthreads();   // staging reads done before mat1 overwrites
    }
}

// ---------------------------------------------------------------------------
// rnn v15 (validated r15): 8-wave j-split + fused head-dot partials,
// conflict-free [kk][lane]x16B h layout, dot after the barrier.
// ---------------------------------------------------------------------------
__global__ __launch_bounds__(512, 1) void rnn_kernel(
    const ushort_t* __restrict__ preF, const ushort_t* __restrict__ preB,
    const ushort_t* __restrict__ whhF, const ushort_t* __restrict__ whhB,
    const float* __restrict__ fcw, const int* __restrict__ norder,
    float* __restrict__ dotP)
{
    __shared__ char hlds[8192];  // 2 x [4 kk][64 lane] x 16B
    const int bid = blockIdx.x;       // 64 blocks = 32 groups x 2 dirs
    const int dir = bid & 1;
    const int s0 = (bid >> 1) * 16;
    const ushort_t* __restrict__ pre = dir ? preB : preF;
    const ushort_t* __restrict__ whh = dir ? whhB : whhF;

    const int tid = threadIdx.x;
    const int w = tid >> 6;           // 0..7 = j-tile
    const int l = tid & 63;
    const int lr = l & 15, lg = l >> 4;

    const int jt = w;
    const int jb = (jt & 3) * 32 + lg * 8 + (jt >> 2) * 4;  // quad base (D layout)

    // A fragments (permuted rows): row = pi(jt, lr)
    bf16x8 A[4];
#pragma unroll
    for (int kk = 0; kk < 4; ++kk) {
        const int row = (jt & 3) * 32 + (lr >> 2) * 8 + (jt >> 2) * 4 + (lr & 3);
        A[kk] = *(const bf16x8*)(whh + (size_t)row * HD + kk * 32 + lg * 8);
    }

    // head weights for this lane's j-quad; lane lr = sample (v5/v8-validated)
    const int n = norder[s0 + lr];
    const float* wrow = fcw + (size_t)n * CD + HS + dir * HD;
    float wg0 = wrow[jb], wg1 = wrow[jb + 1], wg2 = wrow[jb + 2], wg3 = wrow[jb + 3];

    // partial-dot output slice for this (dir, wave)
    float* __restrict__ dotW = dotP + ((size_t)(dir * 8 + w) * TT) * BB;

    const int dt = dir ? -1 : 1;
    const int t0 = dir ? (TT - 1) : 0;
    // m-major pre: per-lane slab base + jb (lane-constant), t*HD steps inside
    const ushort_t* __restrict__ lane_pre = pre + (size_t)(s0 + lr) * (TT * HD) + jb;

    // LDS offsets: read kk*1024 + l*16; write (jt&3)*1024 + l*16 + (jt>>2)*8
    const int rbase = l * 16;
    const int woff = (jt & 3) * 1024 + l * 16 + (jt >> 2) * 8;

    // zero h buffer 0 (h_{-1} = 0): 512 threads x 8B = 4096B
    *(uint2*)(hlds + tid * 8) = (uint2){0u, 0u};

    // depth-3 register prefetch of this wave's pre quad (1 uint2 per step)
    uint2 pA, pB, pC;
    {
        pA = *(const uint2*)(lane_pre + (size_t)t0 * HD);
        pB = *(const uint2*)(lane_pre + (size_t)(t0 + dt) * HD);
        pC = *(const uint2*)(lane_pre + (size_t)(t0 + 2 * dt) * HD);
    }
    __syncthreads();  // once before the loop (full drain fine here)

    int t = t0;
    int cur = 0;

#define RNN_STEP(P)                                                            \
    {                                                                          \
        bf16x8 Bq[4];                                                          \
        _Pragma("unroll")                                                      \
        for (int kk = 0; kk < 4; ++kk)                                         \
            Bq[kk] = *(const bf16x8*)(hlds + cur * 4096 + kk * 1024 + rbase);  \
        f32x4 accA, accB;                                                      \
        accA[0] = bflo(P.x); accA[1] = bfhi(P.x);                              \
        accA[2] = bflo(P.y); accA[3] = bfhi(P.y);                              \
        accB = (f32x4){0.f, 0.f, 0.f, 0.f};                                    \
        {   /* issue prefetch for t+3 early (hides under MFMA) */              \
            const int tp = t + 3 * dt;                                         \
            const int tc = tp < 0 ? 0 : (tp >= TT ? TT - 1 : tp);              \
            P = *(const uint2*)(lane_pre + (size_t)tc * HD);                   \
        }                                                                      \
        accA = __builtin_amdgcn_mfma_f32_16x16x32_bf16(A[0], Bq[0], accA, 0, 0, 0); \
        accB = __builtin_amdgcn_mfma_f32_16x16x32_bf16(A[2], Bq[2], accB, 0, 0, 0); \
        accA = __builtin_amdgcn_mfma_f32_16x16x32_bf16(A[1], Bq[1], accA, 0, 0, 0); \
        accB = __builtin_amdgcn_mfma_f32_16x16x32_bf16(A[3], Bq[3], accB, 0, 0, 0); \
        const float v0 = fmaxf(accA[0] + accB[0], 0.f);                        \
        const float v1 = fmaxf(accA[1] + accB[1], 0.f);                        \
        const float v2 = fmaxf(accA[2] + accB[2], 0.f);                        \
        const float v3 = fmaxf(accA[3] + accB[3], 0.f);                        \
        const uint2 q = {cvt_pk(v0, v1), cvt_pk(v2, v3)};                      \
        *(uint2*)(hlds + (cur ^ 1) * 4096 + woff) = q;                         \
        asm volatile("s_waitcnt lgkmcnt(0)" ::: "memory");                     \
        __builtin_amdgcn_s_barrier();                                          \
        /* head-dot partial AFTER the barrier: overlaps next step's reads */   \
        float dacc = fmaf(v0, wg0, v1 * wg1) + fmaf(v2, wg2, v3 * wg3);        \
        dacc += __shfl_xor(dacc, 16);                                          \
        dacc += __shfl_xor(dacc, 32);                                          \
        if (lg == 0) dotW[(size_t)t * BB + s0 + lr] = dacc;                    \
        t += dt;                                                               \
        cur ^= 1;                                                              \
    }

    for (int it = 0; it < TT / 3; ++it) {
        RNN_STEP(pA);
        RNN_STEP(pB);
        RNN_STEP(pC);
    }
#undef RNN_STEP
}

// ---------------------------------------------------------------------------
// final: out[s*T+t] = relu(ds[s] + sum_{dir,w} dotP[dw][t][s]).
// ---------------------------------------------------------------------------
__global__ __launch_bounds__(512) void final_kernel(
    const float* __restrict__ ds, const float* __restrict__ dotP,
    float* __restrict__ out)
{
    const int t = blockIdx.x;       // < 300
    const int s = threadIdx.x;      // < 512
    float acc = ds[s];
#pragma unroll
    for (int dw = 0; dw < 16; ++dw)
        acc += dotP[((size_t)dw * TT + t) * BB + s];
    out[(size_t)s * TT + t] = fmaxf(acc, 0.f);
}

// ---------------------------------------------------------------------------
extern "C" void kernel_launch(void* const* d_in, const int* in_sizes, int n_in,
                              void* d_out, int out_size, void* d_ws, size_t ws_size,
                              hipStream_t stream)
{
    const float* x_static = (const float*)d_in[0];
    const float* x_dyn    = (const float*)d_in[1];
    const int*   norder   = (const int*)d_in[2];
    const float* w_s1 = (const float*)d_in[3];  const float* b_s1 = (const float*)d_in[4];
    const float* w_s2 = (const float*)d_in[5];  const float* b_s2 = (const float*)d_in[6];
    const float* w_d  = (const float*)d_in[7];  const float* b_d  = (const float*)d_in[8];
    const float* w_ih_f = (const float*)d_in[9];  const float* w_hh_f = (const float*)d_in[10];
    const float* b_ih_f = (const float*)d_in[11]; const float* b_hh_f = (const float*)d_in[12];
    const float* w_ih_b = (const float*)d_in[13]; const float* w_hh_b = (const float*)d_in[14];
    const float* b_ih_b = (const float*)d_in[15]; const float* b_hh_b = (const float*)d_in[16];
    const float* fc_w = (const float*)d_in[17];  const float* fc_b = (const float*)d_in[18];
    float* out = (float*)d_out;

    const size_t PRE_BYTES = (size_t)BB * TT * HD * sizeof(ushort_t);  // 39,321,600
    char* p = (char*)d_ws;
    ushort_t* preF    = (ushort_t*)p;
    ushort_t* preB    = (ushort_t*)(p + PRE_BYTES);
    char* q = p + 2 * PRE_BYTES;
    ushort_t* wd_bf   = (ushort_t*)q;               q += 16384 * sizeof(ushort_t);
    ushort_t* wihf_bf = (ushort_t*)q;               q += 16384 * sizeof(ushort_t);
    ushort_t* wihb_bf = (ushort_t*)q;               q += 16384 * sizeof(ushort_t);
    ushort_t* whhf_bf = (ushort_t*)q;               q += 16384 * sizeof(ushort_t);
    ushort_t* whhb_bf = (ushort_t*)q;               q += 16384 * sizeof(ushort_t);
    float* bsf = (float*)q;                         q += 256 * sizeof(float);
    float* bsb = (float*)q;                         q += 256 * sizeof(float);
    float* ds  = (float*)q;                         q += 512 * sizeof(float);
    float* dotP = (float*)q;                        // [16][300][512] f32 = 9.83 MB

    prep_kernel<<<64, 256, 0, stream>>>(w_d, w_ih_f, w_ih_b, w_hh_f, w_hh_b,
                                        b_ih_f, b_hh_f, b_ih_b, b_hh_b,
                                        wd_bf, wihf_bf, wihb_bf, whhf_bf, whhb_bf, bsf, bsb);
    static_head_kernel<<<BB, 256, 0, stream>>>(x_static, norder, w_s1, b_s1, w_s2, b_s2,
                                               fc_w, fc_b, ds);
    proj_kernel<<<(BB * TT) / 64, 256, 0, stream>>>(x_dyn, wd_bf, b_d, wihf_bf, wihb_bf,
                                                    bsf, bsb, preF, preB);
    rnn_kernel<<<64, 512, 0, stream>>>(preF, preB, whhf_bf, whhb_bf, fc_w, norder, dotP);
    final_kernel<<<TT, 512, 0, stream>>>(ds, dotP, out);
}

// Round 18
// 162.623 us; speedup vs baseline: 1.5080x; 1.5080x over previous
//
#include <hip/hip_runtime.h>
#include <hip/hip_bf16.h>

#define BB 512
#define TT 300
#define IN_S 128
#define IN_D 64
#define HS 256
#define HD 128
#define CD 512  // 2*HD + HS

typedef __attribute__((ext_vector_type(8))) short bf16x8;
typedef __attribute__((ext_vector_type(4))) float f32x4;
typedef __attribute__((ext_vector_type(4))) unsigned uint4_t;
typedef unsigned short ushort_t;

static __device__ __forceinline__ ushort_t f2bf(float x) {
    unsigned u = __builtin_bit_cast(unsigned, x);
    unsigned r = (u + 0x7FFFu + ((u >> 16) & 1u)) >> 16;  // RNE
    return (ushort_t)r;
}
static __device__ __forceinline__ float bflo(unsigned u) {
    return __builtin_bit_cast(float, u << 16);
}
static __device__ __forceinline__ float bfhi(unsigned u) {
    return __builtin_bit_cast(float, u & 0xffff0000u);
}
static __device__ __forceinline__ unsigned cvt_pk(float lo, float hi) {
    unsigned r;
    asm("v_cvt_pk_bf16_f32 %0, %1, %2" : "=v"(r) : "v"(lo), "v"(hi));
    return r;
}

// ---------------------------------------------------------------------------
// prep: f32 weights -> bf16 workspace copies; fused RNN bias sums.
// ---------------------------------------------------------------------------
__global__ __launch_bounds__(256) void prep_kernel(
    const float* __restrict__ wd, const float* __restrict__ wihf, const float* __restrict__ wihb,
    const float* __restrict__ whhf, const float* __restrict__ whhb,
    const float* __restrict__ bif, const float* __restrict__ bhf,
    const float* __restrict__ bib, const float* __restrict__ bhb,
    ushort_t* __restrict__ wd_bf, ushort_t* __restrict__ wihf_bf, ushort_t* __restrict__ wihb_bf,
    ushort_t* __restrict__ whhf_bf, ushort_t* __restrict__ whhb_bf,
    float* __restrict__ bsf, float* __restrict__ bsb)
{
    const int i = blockIdx.x * 256 + threadIdx.x;  // < 16384
    if (i < HD * IN_D) wd_bf[i] = f2bf(wd[i]);
    wihf_bf[i] = f2bf(wihf[i]);
    wihb_bf[i] = f2bf(wihb[i]);
    whhf_bf[i] = f2bf(whhf[i]);
    whhb_bf[i] = f2bf(whhb[i]);
    if (i < HD) { bsf[i] = bif[i] + bhf[i]; bsb[i] = bib[i] + bhb[i]; }
}

// ---------------------------------------------------------------------------
// Kernel A (validated r0): static MLP + static head dot.
// ---------------------------------------------------------------------------
__global__ __launch_bounds__(256) void static_head_kernel(
    const float* __restrict__ xs, const int* __restrict__ norder,
    const float* __restrict__ w1, const float* __restrict__ b1,
    const float* __restrict__ w2, const float* __restrict__ b2,
    const float* __restrict__ fcw, const float* __restrict__ fcb,
    float* __restrict__ ds)
{
    __shared__ float xb[IN_S];
    __shared__ float s1[HS];
    __shared__ float red[4];
    const int b = blockIdx.x, tid = threadIdx.x;
    if (tid < IN_S) xb[tid] = xs[(size_t)b * IN_S + tid];
    __syncthreads();

    float a0 = 0.f, a1 = 0.f, a2 = 0.f, a3 = 0.f;
    {
        const float4* wsrc = (const float4*)(w1 + (size_t)tid * IN_S);
        const float4* x4 = (const float4*)xb;
#pragma unroll
        for (int i = 0; i < IN_S / 4; ++i) {
            float4 w = wsrc[i], x = x4[i];
            a0 = fmaf(w.x, x.x, a0); a1 = fmaf(w.y, x.y, a1);
            a2 = fmaf(w.z, x.z, a2); a3 = fmaf(w.w, x.w, a3);
        }
    }
    s1[tid] = fmaxf(b1[tid] + ((a0 + a1) + (a2 + a3)), 0.f);
    __syncthreads();

    a0 = a1 = a2 = a3 = 0.f;
    {
        const float4* wsrc = (const float4*)(w2 + (size_t)tid * HS);
        const float4* x4 = (const float4*)s1;
#pragma unroll
        for (int i = 0; i < HS / 4; ++i) {
            float4 w = wsrc[i], x = x4[i];
            a0 = fmaf(w.x, x.x, a0); a1 = fmaf(w.y, x.y, a1);
            a2 = fmaf(w.z, x.z, a2); a3 = fmaf(w.w, x.w, a3);
        }
    }
    float s2 = fmaxf(b2[tid] + ((a0 + a1) + (a2 + a3)), 0.f);

    const int n = norder[b];
    float p = s2 * fcw[(size_t)n * CD + tid];
#pragma unroll
    for (int o = 32; o >= 1; o >>= 1) p += __shfl_down(p, o);
    if ((tid & 63) == 0) red[tid >> 6] = p;
    __syncthreads();
    if (tid == 0) ds[b] = red[0] + red[1] + red[2] + red[3] + fcb[n];
}

// ---------------------------------------------------------------------------
// proj v18: v14's validated 128-row structure, but ALL weights hoisted into
// per-wave registers (wave w owns output coltiles {2w,2w+1}; 20 bf16x8 frags
// = 80 VGPR, loaded once). Inner loops contain ONLY ds_read + MFMA — the 1:1
// global-weight-load:MFMA dependency (the 85% stall) is gone. Same swizzles,
// same staging bounce + 1KB-wide stores as v14.
// ---------------------------------------------------------------------------
__global__ __launch_bounds__(256) void proj_kernel(
    const float* __restrict__ xd, const ushort_t* __restrict__ wd_bf,
    const float* __restrict__ bd,
    const ushort_t* __restrict__ wihf_bf, const ushort_t* __restrict__ wihb_bf,
    const float* __restrict__ bsf, const float* __restrict__ bsb,
    ushort_t* __restrict__ preF, ushort_t* __restrict__ preB)
{
    __shared__ char lds[49152];
    char* dbase = lds;            // [128][256B] d-tile, swizzled
    char* xbase = lds + 32768;    // [128][128B] x-tile (16KB), later output staging
    const int tid = threadIdx.x;
    const int m0 = blockIdx.x * 128;
    const int w = tid >> 6, l = tid & 63;
    const int lr = l & 15, lg = l >> 4;
    const int nt0 = 2 * w, nt1 = 2 * w + 1;

    // hoisted weight fragments (loaded once; same addressing as v14's b[nt])
    bf16x8 Wd[2][2];                 // [nt01][kk]
#pragma unroll
    for (int i = 0; i < 2; ++i)
#pragma unroll
        for (int kk = 0; kk < 2; ++kk)
            Wd[i][kk] = *(const bf16x8*)(wd_bf + (size_t)((nt0 + i) * 16 + lr) * IN_D + kk * 32 + lg * 8);
    bf16x8 Wih[2][2][4];             // [mat][nt01][kk]
#pragma unroll
    for (int mat = 0; mat < 2; ++mat) {
        const ushort_t* wm = mat ? wihb_bf : wihf_bf;
#pragma unroll
        for (int i = 0; i < 2; ++i)
#pragma unroll
            for (int kk = 0; kk < 4; ++kk)
                Wih[mat][i][kk] = *(const bf16x8*)(wm + (size_t)((nt0 + i) * 16 + lr) * HD + kk * 32 + lg * 8);
    }

    {   // stage x -> bf16 LDS (v14 verbatim)
        const int row = tid >> 1, half = tid & 1;
        const int swz = (row & 7) << 4;
        const float4* src = (const float4*)(xd + (size_t)(m0 + row) * IN_D + half * 32);
#pragma unroll
        for (int i = 0; i < 2; ++i) {
            const float4 a = src[4 * i], b = src[4 * i + 1], c = src[4 * i + 2], d = src[4 * i + 3];
            const uint4_t v0 = {cvt_pk(a.x, a.y), cvt_pk(a.z, a.w),
                                cvt_pk(b.x, b.y), cvt_pk(b.z, b.w)};
            const uint4_t v1 = {cvt_pk(c.x, c.y), cvt_pk(c.z, c.w),
                                cvt_pk(d.x, d.y), cvt_pk(d.z, d.w)};
            *(uint4_t*)(xbase + ((row * 128 + half * 64 + i * 32) ^ swz)) = v0;
            *(uint4_t*)(xbase + ((row * 128 + half * 64 + i * 32 + 16) ^ swz)) = v1;
        }
    }
    __syncthreads();

    // ---- phase 1: d = relu(x @ wd^T + bd); all 8 rowtiles x this wave's 2 nt
    {
        const float bj0 = bd[nt0 * 16 + lr], bj1 = bd[nt1 * 16 + lr];
        const int col20 = (nt0 * 16 + lr) * 2, col21 = (nt1 * 16 + lr) * 2;
#pragma unroll
        for (int rt = 0; rt < 8; ++rt) {
            f32x4 a0 = {0.f, 0.f, 0.f, 0.f}, a1 = {0.f, 0.f, 0.f, 0.f};
#pragma unroll
            for (int kk = 0; kk < 2; ++kk) {
                const int row = rt * 16 + lr;
                const bf16x8 ax = *(const bf16x8*)(xbase + ((row * 128 + kk * 64 + lg * 16) ^ ((row & 7) << 4)));
                a0 = __builtin_amdgcn_mfma_f32_16x16x32_bf16(ax, Wd[0][kk], a0, 0, 0, 0);
                a1 = __builtin_amdgcn_mfma_f32_16x16x32_bf16(ax, Wd[1][kk], a1, 0, 0, 0);
            }
#pragma unroll
            for (int r = 0; r < 4; ++r) {
                const int row = rt * 16 + lg * 4 + r;
                const int sw = (row & 7) << 4;
                const float v0 = fmaxf(a0[r] + bj0, 0.f);
                const float v1 = fmaxf(a1[r] + bj1, 0.f);
                *(ushort_t*)(dbase + ((row * 256 + col20) ^ sw)) = (ushort_t)cvt_pk(v0, v0);
                *(ushort_t*)(dbase + ((row * 256 + col21) ^ sw)) = (ushort_t)cvt_pk(v1, v1);
            }
        }
    }

    // ---- phase 2: loop (mat, 64-row half): compute, stage in xbase, store wide
#pragma unroll
    for (int mat = 0; mat < 2; ++mat) {
        const float* bs = mat ? bsb : bsf;
        ushort_t* outp = mat ? preB : preF;
        const float bs0 = bs[nt0 * 16 + lr], bs1 = bs[nt1 * 16 + lr];
        const int col20 = (nt0 * 16 + lr) * 2, col21 = (nt1 * 16 + lr) * 2;
#pragma unroll
        for (int half = 0; half < 2; ++half) {
            __syncthreads();  // d ready (1st round) / staging readers done (later)
#pragma unroll
            for (int rt4 = 0; rt4 < 4; ++rt4) {
                const int rt = half * 4 + rt4;
                f32x4 a0 = {0.f, 0.f, 0.f, 0.f}, a1 = {0.f, 0.f, 0.f, 0.f};
#pragma unroll
                for (int kk = 0; kk < 4; ++kk) {
                    const int row = rt * 16 + lr;
                    const bf16x8 ad = *(const bf16x8*)(dbase + ((row * 256 + kk * 64 + lg * 16) ^ ((row & 7) << 4)));
                    a0 = __builtin_amdgcn_mfma_f32_16x16x32_bf16(ad, Wih[mat][0][kk], a0, 0, 0, 0);
                    a1 = __builtin_amdgcn_mfma_f32_16x16x32_bf16(ad, Wih[mat][1][kk], a1, 0, 0, 0);
                }
#pragma unroll
                for (int r = 0; r < 4; ++r) {
                    const int rr = rt4 * 16 + lg * 4 + r;   // staging row 0..63
                    const int sw = (rr & 7) << 4;
                    const float v0 = a0[r] + bs0;
                    const float v1 = a1[r] + bs1;
                    *(ushort_t*)(xbase + ((rr * 256 + col20) ^ sw)) = (ushort_t)cvt_pk(v0, v0);
                    *(ushort_t*)(xbase + ((rr * 256 + col21) ^ sw)) = (ushort_t)cvt_pk(v1, v1);
                }
            }
            __syncthreads();
            // 64 rows x 16 segs of 16B; wave writes 1KB contiguous per instr
#pragma unroll
            for (int k = 0; k < 4; ++k) {
                const int seg = tid + k * 256;            // 0..1023
                const int rr = seg >> 4, sg = seg & 15;
                const uint4_t val = *(const uint4_t*)(xbase + ((rr * 256 + sg * 16) ^ ((rr & 7) << 4)));
                *(uint4_t*)(outp + (size_t)(m0 + half * 64 + rr) * HD + sg * 8) = val;
            }
        }
    }
}

// ---------------------------------------------------------------------------
// rnn v15 (validated r15): 8-wave j-split + fused head-dot partials,
// conflict-free [kk][lane]x16B h layout, dot after the barrier.
// ---------------------------------------------------------------------------
__global__ __launch_bounds__(512, 1) void rnn_kernel(
    const ushort_t* __restrict__ preF, const ushort_t* __restrict__ preB,
    const ushort_t* __restrict__ whhF, const ushort_t* __restrict__ whhB,
    const float* __restrict__ fcw, const int* __restrict__ norder,
    float* __restrict__ dotP)
{
    __shared__ char hlds[8192];  // 2 x [4 kk][64 lane] x 16B
    const int bid = blockIdx.x;       // 64 blocks = 32 groups x 2 dirs
    const int dir = bid & 1;
    const int s0 = (bid >> 1) * 16;
    const ushort_t* __restrict__ pre = dir ? preB : preF;
    const ushort_t* __restrict__ whh = dir ? whhB : whhF;

    const int tid = threadIdx.x;
    const int w = tid >> 6;           // 0..7 = j-tile
    const int l = tid & 63;
    const int lr = l & 15, lg = l >> 4;

    const int jt = w;
    const int jb = (jt & 3) * 32 + lg * 8 + (jt >> 2) * 4;  // quad base (D layout)

    // A fragments (permuted rows): row = pi(jt, lr)
    bf16x8 A[4];
#pragma unroll
    for (int kk = 0; kk < 4; ++kk) {
        const int row = (jt & 3) * 32 + (lr >> 2) * 8 + (jt >> 2) * 4 + (lr & 3);
        A[kk] = *(const bf16x8*)(whh + (size_t)row * HD + kk * 32 + lg * 8);
    }

    // head weights for this lane's j-quad; lane lr = sample (v5/v8-validated)
    const int n = norder[s0 + lr];
    const float* wrow = fcw + (size_t)n * CD + HS + dir * HD;
    float wg0 = wrow[jb], wg1 = wrow[jb + 1], wg2 = wrow[jb + 2], wg3 = wrow[jb + 3];

    // partial-dot output slice for this (dir, wave)
    float* __restrict__ dotW = dotP + ((size_t)(dir * 8 + w) * TT) * BB;

    const int dt = dir ? -1 : 1;
    const int t0 = dir ? (TT - 1) : 0;
    // m-major pre: per-lane slab base + jb (lane-constant), t*HD steps inside
    const ushort_t* __restrict__ lane_pre = pre + (size_t)(s0 + lr) * (TT * HD) + jb;

    // LDS offsets: read kk*1024 + l*16; write (jt&3)*1024 + l*16 + (jt>>2)*8
    const int rbase = l * 16;
    const int woff = (jt & 3) * 1024 + l * 16 + (jt >> 2) * 8;

    // zero h buffer 0 (h_{-1} = 0): 512 threads x 8B = 4096B
    *(uint2*)(hlds + tid * 8) = (uint2){0u, 0u};

    // depth-3 register prefetch of this wave's pre quad (1 uint2 per step)
    uint2 pA, pB, pC;
    {
        pA = *(const uint2*)(lane_pre + (size_t)t0 * HD);
        pB = *(const uint2*)(lane_pre + (size_t)(t0 + dt) * HD);
        pC = *(const uint2*)(lane_pre + (size_t)(t0 + 2 * dt) * HD);
    }
    __syncthreads();  // once before the loop (full drain fine here)

    int t = t0;
    int cur = 0;

#define RNN_STEP(P)                                                            \
    {                                                                          \
        bf16x8 Bq[4];                                                          \
        _Pragma("unroll")                                                      \
        for (int kk = 0; kk < 4; ++kk)                                         \
            Bq[kk] = *(const bf16x8*)(hlds + cur * 4096 + kk * 1024 + rbase);  \
        f32x4 accA, accB;                                                      \
        accA[0] = bflo(P.x); accA[1] = bfhi(P.x);                              \
        accA[2] = bflo(P.y); accA[3] = bfhi(P.y);                              \
        accB = (f32x4){0.f, 0.f, 0.f, 0.f};                                    \
        {   /* issue prefetch for t+3 early (hides under MFMA) */              \
            const int tp = t + 3 * dt;                                         \
            const int tc = tp < 0 ? 0 : (tp >= TT ? TT - 1 : tp);              \
            P = *(const uint2*)(lane_pre + (size_t)tc * HD);                   \
        }                                                                      \
        accA = __builtin_amdgcn_mfma_f32_16x16x32_bf16(A[0], Bq[0], accA, 0, 0, 0); \
        accB = __builtin_amdgcn_mfma_f32_16x16x32_bf16(A[2], Bq[2], accB, 0, 0, 0); \
        accA = __builtin_amdgcn_mfma_f32_16x16x32_bf16(A[1], Bq[1], accA, 0, 0, 0); \
        accB = __builtin_amdgcn_mfma_f32_16x16x32_bf16(A[3], Bq[3], accB, 0, 0, 0); \
        const float v0 = fmaxf(accA[0] + accB[0], 0.f);                        \
        const float v1 = fmaxf(accA[1] + accB[1], 0.f);                        \
        const float v2 = fmaxf(accA[2] + accB[2], 0.f);                        \
        const float v3 = fmaxf(accA[3] + accB[3], 0.f);                        \
        const uint2 q = {cvt_pk(v0, v1), cvt_pk(v2, v3)};                      \
        *(uint2*)(hlds + (cur ^ 1) * 4096 + woff) = q;                         \
        asm volatile("s_waitcnt lgkmcnt(0)" ::: "memory");                     \
        __builtin_amdgcn_s_barrier();                                          \
        /* head-dot partial AFTER the barrier: overlaps next step's reads */   \
        float dacc = fmaf(v0, wg0, v1 * wg1) + fmaf(v2, wg2, v3 * wg3);        \
        dacc += __shfl_xor(dacc, 16);                                          \
        dacc += __shfl_xor(dacc, 32);                                          \
        if (lg == 0) dotW[(size_t)t * BB + s0 + lr] = dacc;                    \
        t += dt;                                                               \
        cur ^= 1;                                                              \
    }

    for (int it = 0; it < TT / 3; ++it) {
        RNN_STEP(pA);
        RNN_STEP(pB);
        RNN_STEP(pC);
    }
#undef RNN_STEP
}

// ---------------------------------------------------------------------------
// final: out[s*T+t] = relu(ds[s] + sum_{dir,w} dotP[dw][t][s]).
// ---------------------------------------------------------------------------
__global__ __launch_bounds__(512) void final_kernel(
    const float* __restrict__ ds, const float* __restrict__ dotP,
    float* __restrict__ out)
{
    const int t = blockIdx.x;       // < 300
    const int s = threadIdx.x;      // < 512
    float acc = ds[s];
#pragma unroll
    for (int dw = 0; dw < 16; ++dw)
        acc += dotP[((size_t)dw * TT + t) * BB + s];
    out[(size_t)s * TT + t] = fmaxf(acc, 0.f);
}

// ---------------------------------------------------------------------------
extern "C" void kernel_launch(void* const* d_in, const int* in_sizes, int n_in,
                              void* d_out, int out_size, void* d_ws, size_t ws_size,
                              hipStream_t stream)
{
    const float* x_static = (const float*)d_in[0];
    const float* x_dyn    = (const float*)d_in[1];
    const int*   norder   = (const int*)d_in[2];
    const float* w_s1 = (const float*)d_in[3];  const float* b_s1 = (const float*)d_in[4];
    const float* w_s2 = (const float*)d_in[5];  const float* b_s2 = (const float*)d_in[6];
    const float* w_d  = (const float*)d_in[7];  const float* b_d  = (const float*)d_in[8];
    const float* w_ih_f = (const float*)d_in[9];  const float* w_hh_f = (const float*)d_in[10];
    const float* b_ih_f = (const float*)d_in[11]; const float* b_hh_f = (const float*)d_in[12];
    const float* w_ih_b = (const float*)d_in[13]; const float* w_hh_b = (const float*)d_in[14];
    const float* b_ih_b = (const float*)d_in[15]; const float* b_hh_b = (const float*)d_in[16];
    const float* fc_w = (const float*)d_in[17];  const float* fc_b = (const float*)d_in[18];
    float* out = (float*)d_out;

    const size_t PRE_BYTES = (size_t)BB * TT * HD * sizeof(ushort_t);  // 39,321,600
    char* p = (char*)d_ws;
    ushort_t* preF    = (ushort_t*)p;
    ushort_t* preB    = (ushort_t*)(p + PRE_BYTES);
    char* q = p + 2 * PRE_BYTES;
    ushort_t* wd_bf   = (ushort_t*)q;               q += 16384 * sizeof(ushort_t);
    ushort_t* wihf_bf = (ushort_t*)q;               q += 16384 * sizeof(ushort_t);
    ushort_t* wihb_bf = (ushort_t*)q;               q += 16384 * sizeof(ushort_t);
    ushort_t* whhf_bf = (ushort_t*)q;               q += 16384 * sizeof(ushort_t);
    ushort_t* whhb_bf = (ushort_t*)q;               q += 16384 * sizeof(ushort_t);
    float* bsf = (float*)q;                         q += 256 * sizeof(float);
    float* bsb = (float*)q;                         q += 256 * sizeof(float);
    float* ds  = (float*)q;                         q += 512 * sizeof(float);
    float* dotP = (float*)q;                        // [16][300][512] f32 = 9.83 MB

    prep_kernel<<<64, 256, 0, stream>>>(w_d, w_ih_f, w_ih_b, w_hh_f, w_hh_b,
                                        b_ih_f, b_hh_f, b_ih_b, b_hh_b,
                                        wd_bf, wihf_bf, wihb_bf, whhf_bf, whhb_bf, bsf, bsb);
    static_head_kernel<<<BB, 256, 0, stream>>>(x_static, norder, w_s1, b_s1, w_s2, b_s2,
                                               fc_w, fc_b, ds);
    proj_kernel<<<(BB * TT) / 128, 256, 0, stream>>>(x_dyn, wd_bf, b_d, wihf_bf, wihb_bf,
                                                     bsf, bsb, preF, preB);
    rnn_kernel<<<64, 512, 0, stream>>>(preF, preB, whhf_bf, whhb_bf, fc_w, norder, dotP);
    final_kernel<<<TT, 512, 0, stream>>>(ds, dotP, out);
}